// Round 5
// baseline (1250.833 us; speedup 1.0000x reference)
//
#include <hip/hip_runtime.h>
#include <hip/hip_bf16.h>

typedef __hip_bfloat16 bf16;
typedef float f32x4 __attribute__((ext_vector_type(4)));
typedef short bf16x8 __attribute__((ext_vector_type(8)));
typedef short short4v __attribute__((ext_vector_type(4)));

#define NTOK 100352   // 32*56*56 tokens = 2048 windows * 49
#define CC 192
#define HIDN 768

__device__ __forceinline__ float b2f(unsigned short u) {
    union { unsigned int u32; float f; } x; x.u32 = ((unsigned int)u) << 16; return x.f;
}
__device__ __forceinline__ unsigned short f2b(float f) {
    union { float f; unsigned int u; } x; x.f = f;
    unsigned int r = x.u + 0x7FFF + ((x.u >> 16) & 1);
    return (unsigned short)(r >> 16);
}

// ---------------- weight prep: fp32 src [R][C] -> bf16 dst[c*R + r] = src[r][c] ----------------
__global__ void transpose_k(const float* __restrict__ src, bf16* __restrict__ dst, int R, int C) {
    int idx = blockIdx.x * 256 + threadIdx.x;
    if (idx >= R * C) return;
    int r = idx / C, c = idx % C;
    dst[(size_t)c * R + r] = __float2bfloat16(src[idx]);
}

// ---------------- LayerNorm (wave per token) -> bf16 rows.
// GATHER=true: src fp32 x [B,H,W,C], gather roll(-3,-3)+partition -> xw token order.
// GATHER=false: src fp32 rows (y in d_out), linear order. ----------------
template<bool GATHER>
__global__ __launch_bounds__(256) void ln_k(const float* __restrict__ src,
                                            const float* __restrict__ gamma,
                                            const float* __restrict__ beta,
                                            bf16* __restrict__ dst) {
    int wave = threadIdx.x >> 6, lane = threadIdx.x & 63;
    int t = blockIdx.x * 4 + wave;           // output token index
    size_t srow;
    if (GATHER) {
        int w = t / 49, n = t % 49;
        int b = w >> 6, wl = w & 63, hb = wl >> 3, wb = wl & 7;
        int i = n / 7, j = n % 7;
        int sh = hb * 7 + i + 3; if (sh >= 56) sh -= 56;   // roll(-3): src=(dst+3)%56
        int sw = wb * 7 + j + 3; if (sw >= 56) sw -= 56;
        srow = ((size_t)(b * 56 + sh) * 56 + sw) * CC;
    } else {
        srow = (size_t)t * CC;
    }
    float v[4];
    int c = lane * 4;
    float sum = 0.f, sq = 0.f;
    if (lane < 48) {
        f32x4 d = *(const f32x4*)(src + srow + c);
        #pragma unroll
        for (int q = 0; q < 4; ++q) { v[q] = d[q]; sum += v[q]; sq += v[q] * v[q]; }
    }
    #pragma unroll
    for (int off = 1; off < 64; off <<= 1) { sum += __shfl_xor(sum, off); sq += __shfl_xor(sq, off); }
    float mu = sum * (1.0f / 192.0f);
    float var = sq * (1.0f / 192.0f) - mu * mu;
    float rstd = rsqrtf(var + 1e-5f);
    if (lane < 48) {
        f32x4 gg = *(const f32x4*)(gamma + c);
        f32x4 bb = *(const f32x4*)(beta + c);
        short4v o;
        #pragma unroll
        for (int q = 0; q < 4; ++q) {
            float val = (v[q] - mu) * rstd * gg[q] + bb[q];
            o[q] = (short)f2b(val);
        }
        *(short4v*)(dst + (size_t)t * CC + c) = o;
    }
}

// ---------------- MFMA GEMM: C[M,N] = X[M,K] @ W[K,N] (+bias fp32, epilogue). WT = W^T [N,K] bf16.
// Wave computes one 16x16 tile; 4 waves stacked in M; grid.y covers N in chunks of 64.
// D frag: lane l, reg r -> row (l>>4)*4 + r, col l&15.  (validated: MFMA==VALU bisect, r3/r4)
// EPI 0: +bias -> bf16 outb
// EPI 1: +bias, window-reverse+roll(+3,+3) scatter, outf[dst] = xres[dst] + val (fp32 y in d_out)
// EPI 2: +bias, exact gelu -> bf16 outb
// EPI 3: +bias + yin(fp32) -> fp32 outf (in-place RMW on d_out rows)
template<int EPI>
__global__ __launch_bounds__(256) void gemm_k(
    const bf16* __restrict__ X, const bf16* __restrict__ WT,
    const float* __restrict__ bias, int K, int N,
    bf16* __restrict__ outb, float* __restrict__ outf,
    const float* __restrict__ xres, const float* __restrict__ yin, int mbase)
{
    int wave = threadIdx.x >> 6, lane = threadIdx.x & 63;
    int tm = (blockIdx.x * 4 + wave) * 16;
    int tn0 = blockIdx.y * 64;
    int r = lane & 15, g = lane >> 4;
    const bf16* xrow = X + (size_t)(tm + r) * K + g * 8;
    const bf16* wrow = WT + (size_t)(tn0 + r) * K + g * 8;
    f32x4 acc[4] = {};
    for (int kk = 0; kk < K; kk += 32) {
        bf16x8 a = *(const bf16x8*)(xrow + kk);
        #pragma unroll
        for (int t = 0; t < 4; ++t) {
            bf16x8 b = *(const bf16x8*)(wrow + (size_t)(t * 16) * K + kk);
            acc[t] = __builtin_amdgcn_mfma_f32_16x16x32_bf16(a, b, acc[t], 0, 0, 0);
        }
    }
    #pragma unroll
    for (int t = 0; t < 4; ++t) {
        int col = tn0 + t * 16 + r;
        float bv = bias[col];
        #pragma unroll
        for (int rg = 0; rg < 4; ++rg) {
            int m = tm + g * 4 + rg;
            float val = acc[t][rg] + bv;
            if (EPI == 0) {
                outb[(size_t)m * N + col] = __float2bfloat16(val);
            } else if (EPI == 1) {
                int gm = mbase + m;
                int w = gm / 49, n = gm % 49;
                int b_ = w >> 6, wl = w & 63, hb = wl >> 3, wb = wl & 7;
                int i = n / 7, j = n % 7;
                int oh = hb * 7 + i + 3; if (oh >= 56) oh -= 56;   // roll(+3)
                int ow = wb * 7 + j + 3; if (ow >= 56) ow -= 56;
                size_t dst = ((size_t)(b_ * 56 + oh) * 56 + ow) * CC + col;
                outf[dst] = xres[dst] + val;
            } else if (EPI == 2) {
                float gv = 0.5f * val * (1.0f + erff(val * 0.70710678118f));
                outb[(size_t)m * N + col] = __float2bfloat16(gv);
            } else {
                outf[(size_t)m * N + col] = val + yin[(size_t)m * N + col];
            }
        }
    }
}

// ---------------- Attention: one wave per (window, head), chunk-local pointers.
// Chunk base is a multiple of 64 windows, so region ids from (local&63) match global. ----------------
__global__ __launch_bounds__(64) void attn_k(const bf16* __restrict__ qkv,
                                             const float* __restrict__ btab,
                                             bf16* __restrict__ out)
{
    int w = blockIdx.x, head = blockIdx.y;
    int tid = threadIdx.x;
    __shared__ float ks[49 * 32];
    __shared__ float vs[49 * 32];
    __shared__ int regid[49];
    for (int idx = tid; idx < 49 * 32; idx += 64) {
        int n = idx >> 5, d = idx & 31;
        size_t base = ((size_t)(w * 49 + n)) * 576 + head * 32 + d;
        ks[idx] = __bfloat162float(qkv[base + 192]);
        vs[idx] = __bfloat162float(qkv[base + 384]);
    }
    if (tid < 49) {
        int wl = w & 63, hb = wl >> 3, wb = wl & 7;
        int i = tid / 7, j = tid % 7;
        int gh = hb * 7 + i, gw = wb * 7 + j;
        int rh = gh < 49 ? 0 : (gh < 53 ? 1 : 2);
        int rw = gw < 49 ? 0 : (gw < 53 ? 1 : 2);
        regid[tid] = rh * 3 + rw;
    }
    __syncthreads();
    if (tid >= 49) return;
    int ln = tid;
    float q[32];
    {
        size_t base = ((size_t)(w * 49 + ln)) * 576 + head * 32;
        const float scale = 0.17677669529663689f;  // 32^-0.5
        #pragma unroll
        for (int d = 0; d < 32; ++d) q[d] = __bfloat162float(qkv[base + d]) * scale;
    }
    int i1 = ln / 7, j1 = ln % 7;
    int myreg = regid[ln];
    float s[49];
    #pragma unroll
    for (int m = 0; m < 49; ++m) {
        float acc = 0.f;
        #pragma unroll
        for (int d = 0; d < 32; ++d) acc += q[d] * ks[m * 32 + d];
        const int i2 = m / 7, j2 = m % 7;
        int bidx = (i1 - i2 + 6) * 13 + (j1 - j2 + 6);
        acc += btab[bidx * 6 + head];
        if (regid[m] != myreg) acc -= 100.0f;
        s[m] = acc;
    }
    float mx = -1e30f;
    #pragma unroll
    for (int m = 0; m < 49; ++m) mx = fmaxf(mx, s[m]);
    float ssum = 0.f;
    #pragma unroll
    for (int m = 0; m < 49; ++m) { s[m] = __expf(s[m] - mx); ssum += s[m]; }
    float inv = 1.0f / ssum;
    float o[32];
    #pragma unroll
    for (int d = 0; d < 32; ++d) o[d] = 0.f;
    #pragma unroll
    for (int m = 0; m < 49; ++m) {
        float p = s[m];
        #pragma unroll
        for (int d = 0; d < 32; ++d) o[d] += p * vs[m * 32 + d];
    }
    size_t ob = ((size_t)(w * 49 + ln)) * CC + head * 32;
    #pragma unroll
    for (int d = 0; d < 32; ++d) out[ob + d] = __float2bfloat16(o[d] * inv);
}

// ---------------- launch ----------------
extern "C" void kernel_launch(void* const* d_in, const int* in_sizes, int n_in,
                              void* d_out, int out_size, void* d_ws, size_t ws_size,
                              hipStream_t stream) {
    const float* x      = (const float*)d_in[0];
    const float* n1g    = (const float*)d_in[1];
    const float* n1b    = (const float*)d_in[2];
    const float* qkv_w  = (const float*)d_in[3];
    const float* qkv_b  = (const float*)d_in[4];
    const float* proj_w = (const float*)d_in[5];
    const float* proj_b = (const float*)d_in[6];
    const float* btab   = (const float*)d_in[7];
    const float* n2g    = (const float*)d_in[8];
    const float* n2b    = (const float*)d_in[9];
    const float* fc1_w  = (const float*)d_in[10];
    const float* fc1_b  = (const float*)d_in[11];
    const float* fc2_w  = (const float*)d_in[12];
    const float* fc2_b  = (const float*)d_in[13];

    char* ws = (char*)d_ws;
    // 8 chunks of 256 windows = 12544 tokens.
    //  xw   [0, 38535168)          bf16 [100352][192]  (LN1 out; reused as LN2 out m)
    //  buf  [38535168, 57802752)   qkv bf16 [12544][576] + att bf16 [12544][192]
    //                              (MLP phase: hid bf16 [12544][768], same bytes)
    //  wt   [57802752, 58687488)   transposed bf16 weights
    //  y (fp32) lives in d_out: EPI1 writes every element once, EPI3 RMWs once.
    const size_t XW_OFF  = 0;
    const size_t BUF_OFF = 38535168;
    const size_t ATT_OFF = 38535168 + 14450688;   // qkv chunk = 12544*576*2
    const size_t WT_OFF  = 57802752;
    if (ws_size < 58687488ull) return;   // diagnostic: zeros signature (absmax ~5.59)

    bf16* xw   = (bf16*)(ws + XW_OFF);
    bf16* mbuf = (bf16*)(ws + XW_OFF);       // reuses xw after attn phase
    bf16* qkvc = (bf16*)(ws + BUF_OFF);
    bf16* attc = (bf16*)(ws + ATT_OFF);
    bf16* hidc = (bf16*)(ws + BUF_OFF);      // MLP phase reuse
    float* yf  = (float*)d_out;              // fp32 residual accumulator == final output
    bf16* wt   = (bf16*)(ws + WT_OFF);
    bf16* qkv_wT  = wt;                       // [576][192]
    bf16* proj_wT = wt + 110592;              // [192][192]
    bf16* fc1_wT  = wt + 147456;              // [768][192]
    bf16* fc2_wT  = wt + 294912;              // [192][768]

    transpose_k<<<dim3(432), 256, 0, stream>>>(qkv_w, qkv_wT, 192, 576);
    transpose_k<<<dim3(144), 256, 0, stream>>>(proj_w, proj_wT, 192, 192);
    transpose_k<<<dim3(576), 256, 0, stream>>>(fc1_w, fc1_wT, 192, 768);
    transpose_k<<<dim3(576), 256, 0, stream>>>(fc2_w, fc2_wT, 768, 192);

    ln_k<true><<<NTOK / 4, 256, 0, stream>>>(x, n1g, n1b, xw);

    for (int c = 0; c < 8; ++c) {
        gemm_k<0><<<dim3(196, 9), 256, 0, stream>>>(
            xw + (size_t)c * 12544 * CC, qkv_wT, qkv_b, 192, 576,
            qkvc, nullptr, nullptr, nullptr, 0);
        attn_k<<<dim3(256, 6), 64, 0, stream>>>(qkvc, btab, attc);
        gemm_k<1><<<dim3(196, 3), 256, 0, stream>>>(
            attc, proj_wT, proj_b, 192, 192, nullptr, yf, x, nullptr, c * 12544);
    }

    ln_k<false><<<NTOK / 4, 256, 0, stream>>>(yf, n2g, n2b, mbuf);

    for (int c = 0; c < 8; ++c) {
        size_t roff = (size_t)c * 12544 * CC;
        gemm_k<2><<<dim3(196, 12), 256, 0, stream>>>(
            mbuf + roff, fc1_wT, fc1_b, 192, 768, hidc, nullptr, nullptr, nullptr, 0);
        gemm_k<3><<<dim3(196, 3), 256, 0, stream>>>(
            hidc, fc2_wT, fc2_b, 768, 192, nullptr, yf + roff, nullptr, yf + roff, 0);
    }
}

// Round 6
// 679.911 us; speedup vs baseline: 1.8397x; 1.8397x over previous
//
#include <hip/hip_runtime.h>
#include <hip/hip_bf16.h>

typedef __hip_bfloat16 bf16;
typedef float f32x4 __attribute__((ext_vector_type(4)));
typedef short bf16x8 __attribute__((ext_vector_type(8)));
typedef short short4v __attribute__((ext_vector_type(4)));

#define NTOK 100352   // 32*56*56 tokens = 2048 windows * 49
#define CC 192
#define HIDN 768

__device__ __forceinline__ float b2f(unsigned short u) {
    union { unsigned int u32; float f; } x; x.u32 = ((unsigned int)u) << 16; return x.f;
}
__device__ __forceinline__ unsigned short f2b(float f) {
    union { float f; unsigned int u; } x; x.f = f;
    unsigned int r = x.u + 0x7FFF + ((x.u >> 16) & 1);
    return (unsigned short)(r >> 16);
}

typedef __attribute__((address_space(1))) const unsigned char gas_u8;
typedef __attribute__((address_space(3))) unsigned char las_u8;
__device__ __forceinline__ void gload_lds16(const void* g, void* l) {
    __builtin_amdgcn_global_load_lds((gas_u8*)g, (las_u8*)l, 16, 0, 0);
}

// ---------------- weight prep: fp32 src [R][C] -> bf16 dst[c*R + r] = src[r][c] ----------------
__global__ void transpose_k(const float* __restrict__ src, bf16* __restrict__ dst, int R, int C) {
    int idx = blockIdx.x * 256 + threadIdx.x;
    if (idx >= R * C) return;
    int r = idx / C, c = idx % C;
    dst[(size_t)c * R + r] = __float2bfloat16(src[idx]);
}

// ---------------- LayerNorm (wave per token) -> bf16 rows. ----------------
template<bool GATHER>
__global__ __launch_bounds__(256) void ln_k(const float* __restrict__ src,
                                            const float* __restrict__ gamma,
                                            const float* __restrict__ beta,
                                            bf16* __restrict__ dst) {
    int wave = threadIdx.x >> 6, lane = threadIdx.x & 63;
    int t = blockIdx.x * 4 + wave;           // output token index
    size_t srow;
    if (GATHER) {
        int w = t / 49, n = t % 49;
        int b = w >> 6, wl = w & 63, hb = wl >> 3, wb = wl & 7;
        int i = n / 7, j = n % 7;
        int sh = hb * 7 + i + 3; if (sh >= 56) sh -= 56;   // roll(-3): src=(dst+3)%56
        int sw = wb * 7 + j + 3; if (sw >= 56) sw -= 56;
        srow = ((size_t)(b * 56 + sh) * 56 + sw) * CC;
    } else {
        srow = (size_t)t * CC;
    }
    float v[4];
    int c = lane * 4;
    float sum = 0.f, sq = 0.f;
    if (lane < 48) {
        f32x4 d = *(const f32x4*)(src + srow + c);
        #pragma unroll
        for (int q = 0; q < 4; ++q) { v[q] = d[q]; sum += v[q]; sq += v[q] * v[q]; }
    }
    #pragma unroll
    for (int off = 1; off < 64; off <<= 1) { sum += __shfl_xor(sum, off); sq += __shfl_xor(sq, off); }
    float mu = sum * (1.0f / 192.0f);
    float var = sq * (1.0f / 192.0f) - mu * mu;
    float rstd = rsqrtf(var + 1e-5f);
    if (lane < 48) {
        f32x4 gg = *(const f32x4*)(gamma + c);
        f32x4 bb = *(const f32x4*)(beta + c);
        short4v o;
        #pragma unroll
        for (int q = 0; q < 4; ++q) {
            float val = (v[q] - mu) * rstd * gg[q] + bb[q];
            o[q] = (short)f2b(val);
        }
        *(short4v*)(dst + (size_t)t * CC + c) = o;
    }
}

// ---------------- Tiled MFMA GEMM: C[M,N] = X[M,K] @ W[K,N] (+bias, epilogue). WT = W^T [N,K].
// Block: 256 thr (4 waves), tile BM=128 x BN=64, BK=64, double-buffered LDS via global_load_lds
// (linear dest + inverse-swizzled source; reads XOR-swizzled: rule #21 / T2).
// Wave (w1=w>>1, w0=w&1) computes 64x32: 4 m-frags x 2 n-frags of 16x16x32 MFMA.
// D frag: col=lane&15, row=(lane>>4)*4+reg (validated r3/r4).
// grid.x = N/64, grid.y = M/128 (adjacent blocks share A-tile).
template<int EPI>
__global__ __launch_bounds__(256) void gemm_t(
    const bf16* __restrict__ X, const bf16* __restrict__ WT,
    const float* __restrict__ bias, int K, int N,
    bf16* __restrict__ outb, float* __restrict__ outf,
    const float* __restrict__ xres, const float* __restrict__ yin, int mbase)
{
    __shared__ bf16 As[2][128 * 64];   // 16 KiB each
    __shared__ bf16 Bs[2][64 * 64];    // 8 KiB each
    const int tid = threadIdx.x;
    const int w = tid >> 6, lane = tid & 63;
    const int w0 = w & 1, w1 = w >> 1;
    const int tn0 = blockIdx.x * 64;
    const int tm0 = blockIdx.y * 128;
    const int r16 = lane & 15, g8 = (lane >> 4) * 8;

    // stage one BK=64 tile pair into buffer `buf` at global k offset kk
    auto stage = [&](int buf, int kk) {
        #pragma unroll
        for (int j = 0; j < 4; ++j) {            // A: 1024 chunks of 16B, 16 issues
            int c = (w * 4 + j) * 64 + lane;
            int l = c ^ ((c >> 3) & 7);          // inverse swizzle on source
            const bf16* g = X + (size_t)(tm0 + (c >> 3)) * K + kk + (l & 7) * 8;
            gload_lds16(g, (char*)&As[buf][0] + (size_t)(w * 4 + j) * 1024);
        }
        #pragma unroll
        for (int j = 0; j < 2; ++j) {            // B: 512 chunks, 8 issues
            int c = (w * 2 + j) * 64 + lane;
            int l = c ^ ((c >> 3) & 7);
            const bf16* g = WT + (size_t)(tn0 + (c >> 3)) * K + kk + (l & 7) * 8;
            gload_lds16(g, (char*)&Bs[buf][0] + (size_t)(w * 2 + j) * 1024);
        }
    };

    f32x4 acc[4][2] = {};
    const int nt = K >> 6;
    stage(0, 0);
    __syncthreads();
    for (int t = 0; t < nt; ++t) {
        int buf = t & 1;
        if (t + 1 < nt) stage(buf ^ 1, (t + 1) << 6);
        const char* ab = (const char*)&As[buf][0];
        const char* bb_ = (const char*)&Bs[buf][0];
        #pragma unroll
        for (int k32 = 0; k32 < 2; ++k32) {
            int kcolb = k32 * 64 + g8 * 2;       // byte offset of k-slice
            bf16x8 a[4], b[2];
            #pragma unroll
            for (int m = 0; m < 4; ++m) {
                int row = w1 * 64 + m * 16 + r16;
                int byte = row * 128 + kcolb;
                a[m] = *(const bf16x8*)(ab + (byte ^ ((row & 7) << 4)));
            }
            #pragma unroll
            for (int n = 0; n < 2; ++n) {
                int row = w0 * 32 + n * 16 + r16;
                int byte = row * 128 + kcolb;
                b[n] = *(const bf16x8*)(bb_ + (byte ^ ((row & 7) << 4)));
            }
            #pragma unroll
            for (int m = 0; m < 4; ++m)
                #pragma unroll
                for (int n = 0; n < 2; ++n)
                    acc[m][n] = __builtin_amdgcn_mfma_f32_16x16x32_bf16(a[m], b[n], acc[m][n], 0, 0, 0);
        }
        __syncthreads();
    }

    #pragma unroll
    for (int n = 0; n < 2; ++n) {
        int col = tn0 + w0 * 32 + n * 16 + r16;
        float bv = bias[col];
        #pragma unroll
        for (int m = 0; m < 4; ++m) {
            #pragma unroll
            for (int r = 0; r < 4; ++r) {
                int mm = tm0 + w1 * 64 + m * 16 + (lane >> 4) * 4 + r;
                float val = acc[m][n][r] + bv;
                if (EPI == 0) {
                    outb[(size_t)mm * N + col] = __float2bfloat16(val);
                } else if (EPI == 1) {
                    int gm = mbase + mm;
                    int ww = gm / 49, nn = gm % 49;
                    int b_ = ww >> 6, wl = ww & 63, hb = wl >> 3, wb = wl & 7;
                    int i = nn / 7, j = nn % 7;
                    int oh = hb * 7 + i + 3; if (oh >= 56) oh -= 56;   // roll(+3)
                    int ow = wb * 7 + j + 3; if (ow >= 56) ow -= 56;
                    size_t dst = ((size_t)(b_ * 56 + oh) * 56 + ow) * CC + col;
                    outf[dst] = xres[dst] + val;
                } else if (EPI == 2) {
                    float gv = 0.5f * val * (1.0f + erff(val * 0.70710678118f));
                    outb[(size_t)mm * N + col] = __float2bfloat16(gv);
                } else {
                    outf[(size_t)mm * N + col] = val + yin[(size_t)mm * N + col];
                }
            }
        }
    }
}

// ---------------- Attention: one wave per (window, head), chunk-local pointers. ----------------
__global__ __launch_bounds__(64) void attn_k(const bf16* __restrict__ qkv,
                                             const float* __restrict__ btab,
                                             bf16* __restrict__ out)
{
    int w = blockIdx.x, head = blockIdx.y;
    int tid = threadIdx.x;
    __shared__ float ks[49 * 32];
    __shared__ float vs[49 * 32];
    __shared__ int regid[49];
    for (int idx = tid; idx < 49 * 32; idx += 64) {
        int n = idx >> 5, d = idx & 31;
        size_t base = ((size_t)(w * 49 + n)) * 576 + head * 32 + d;
        ks[idx] = __bfloat162float(qkv[base + 192]);
        vs[idx] = __bfloat162float(qkv[base + 384]);
    }
    if (tid < 49) {
        int wl = w & 63, hb = wl >> 3, wb = wl & 7;
        int i = tid / 7, j = tid % 7;
        int gh = hb * 7 + i, gw = wb * 7 + j;
        int rh = gh < 49 ? 0 : (gh < 53 ? 1 : 2);
        int rw = gw < 49 ? 0 : (gw < 53 ? 1 : 2);
        regid[tid] = rh * 3 + rw;
    }
    __syncthreads();
    if (tid >= 49) return;
    int ln = tid;
    float q[32];
    {
        size_t base = ((size_t)(w * 49 + ln)) * 576 + head * 32;
        const float scale = 0.17677669529663689f;  // 32^-0.5
        #pragma unroll
        for (int d = 0; d < 32; ++d) q[d] = __bfloat162float(qkv[base + d]) * scale;
    }
    int i1 = ln / 7, j1 = ln % 7;
    int myreg = regid[ln];
    float s[49];
    #pragma unroll
    for (int m = 0; m < 49; ++m) {
        float acc = 0.f;
        #pragma unroll
        for (int d = 0; d < 32; ++d) acc += q[d] * ks[m * 32 + d];
        const int i2 = m / 7, j2 = m % 7;
        int bidx = (i1 - i2 + 6) * 13 + (j1 - j2 + 6);
        acc += btab[bidx * 6 + head];
        if (regid[m] != myreg) acc -= 100.0f;
        s[m] = acc;
    }
    float mx = -1e30f;
    #pragma unroll
    for (int m = 0; m < 49; ++m) mx = fmaxf(mx, s[m]);
    float ssum = 0.f;
    #pragma unroll
    for (int m = 0; m < 49; ++m) { s[m] = __expf(s[m] - mx); ssum += s[m]; }
    float inv = 1.0f / ssum;
    float o[32];
    #pragma unroll
    for (int d = 0; d < 32; ++d) o[d] = 0.f;
    #pragma unroll
    for (int m = 0; m < 49; ++m) {
        float p = s[m];
        #pragma unroll
        for (int d = 0; d < 32; ++d) o[d] += p * vs[m * 32 + d];
    }
    size_t ob = ((size_t)(w * 49 + ln)) * CC + head * 32;
    #pragma unroll
    for (int d = 0; d < 32; ++d) out[ob + d] = __float2bfloat16(o[d] * inv);
}

// ---------------- launch ----------------
extern "C" void kernel_launch(void* const* d_in, const int* in_sizes, int n_in,
                              void* d_out, int out_size, void* d_ws, size_t ws_size,
                              hipStream_t stream) {
    const float* x      = (const float*)d_in[0];
    const float* n1g    = (const float*)d_in[1];
    const float* n1b    = (const float*)d_in[2];
    const float* qkv_w  = (const float*)d_in[3];
    const float* qkv_b  = (const float*)d_in[4];
    const float* proj_w = (const float*)d_in[5];
    const float* proj_b = (const float*)d_in[6];
    const float* btab   = (const float*)d_in[7];
    const float* n2g    = (const float*)d_in[8];
    const float* n2b    = (const float*)d_in[9];
    const float* fc1_w  = (const float*)d_in[10];
    const float* fc1_b  = (const float*)d_in[11];
    const float* fc2_w  = (const float*)d_in[12];
    const float* fc2_b  = (const float*)d_in[13];

    char* ws = (char*)d_ws;
    // 8 chunks of 256 windows = 12544 tokens = 98 M-tiles of 128.
    //  xw   [0, 38535168)          bf16 [100352][192]  (LN1 out; reused as LN2 out m)
    //  buf  [38535168, 57802752)   qkv bf16 [12544][576] + att bf16 [12544][192]
    //                              (MLP phase: hid bf16 [12544][768], same bytes)
    //  wt   [57802752, 58687488)   transposed bf16 weights
    //  y (fp32) lives in d_out: EPI1 writes every element once, EPI3 RMWs once.
    const size_t XW_OFF  = 0;
    const size_t BUF_OFF = 38535168;
    const size_t ATT_OFF = 38535168 + 14450688;   // qkv chunk = 12544*576*2
    const size_t WT_OFF  = 57802752;
    if (ws_size < 58687488ull) return;   // diagnostic: zeros signature (absmax ~5.59)

    bf16* xw   = (bf16*)(ws + XW_OFF);
    bf16* mbuf = (bf16*)(ws + XW_OFF);       // reuses xw after attn phase
    bf16* qkvc = (bf16*)(ws + BUF_OFF);
    bf16* attc = (bf16*)(ws + ATT_OFF);
    bf16* hidc = (bf16*)(ws + BUF_OFF);      // MLP phase reuse
    float* yf  = (float*)d_out;              // fp32 residual accumulator == final output
    bf16* wt   = (bf16*)(ws + WT_OFF);
    bf16* qkv_wT  = wt;                       // [576][192]
    bf16* proj_wT = wt + 110592;              // [192][192]
    bf16* fc1_wT  = wt + 147456;              // [768][192]
    bf16* fc2_wT  = wt + 294912;              // [192][768]

    transpose_k<<<dim3(432), 256, 0, stream>>>(qkv_w, qkv_wT, 192, 576);
    transpose_k<<<dim3(144), 256, 0, stream>>>(proj_w, proj_wT, 192, 192);
    transpose_k<<<dim3(576), 256, 0, stream>>>(fc1_w, fc1_wT, 192, 768);
    transpose_k<<<dim3(576), 256, 0, stream>>>(fc2_w, fc2_wT, 768, 192);

    ln_k<true><<<NTOK / 4, 256, 0, stream>>>(x, n1g, n1b, xw);

    for (int c = 0; c < 8; ++c) {
        gemm_t<0><<<dim3(9, 98), 256, 0, stream>>>(
            xw + (size_t)c * 12544 * CC, qkv_wT, qkv_b, 192, 576,
            qkvc, nullptr, nullptr, nullptr, 0);
        attn_k<<<dim3(256, 6), 64, 0, stream>>>(qkvc, btab, attc);
        gemm_t<1><<<dim3(3, 98), 256, 0, stream>>>(
            attc, proj_wT, proj_b, 192, 192, nullptr, yf, x, nullptr, c * 12544);
    }

    ln_k<false><<<NTOK / 4, 256, 0, stream>>>(yf, n2g, n2b, mbuf);

    for (int c = 0; c < 8; ++c) {
        size_t roff = (size_t)c * 12544 * CC;
        gemm_t<2><<<dim3(12, 98), 256, 0, stream>>>(
            mbuf + roff, fc1_wT, fc1_b, 192, 768, hidc, nullptr, nullptr, nullptr, 0);
        gemm_t<3><<<dim3(3, 98), 256, 0, stream>>>(
            hidc, fc2_wT, fc2_b, 768, 192, nullptr, yf + roff, nullptr, yf + roff, 0);
    }
}

// Round 7
// 472.906 us; speedup vs baseline: 2.6450x; 1.4377x over previous
//
#include <hip/hip_runtime.h>
#include <hip/hip_bf16.h>

typedef __hip_bfloat16 bf16;
typedef float f32x4 __attribute__((ext_vector_type(4)));
typedef short bf16x8 __attribute__((ext_vector_type(8)));
typedef short short4v __attribute__((ext_vector_type(4)));

#define NTOK 100352   // 32*56*56 tokens = 2048 windows * 49
#define CC 192
#define HIDN 768

__device__ __forceinline__ float b2f(unsigned short u) {
    union { unsigned int u32; float f; } x; x.u32 = ((unsigned int)u) << 16; return x.f;
}
__device__ __forceinline__ unsigned short f2b(float f) {
    union { float f; unsigned int u; } x; x.f = f;
    unsigned int r = x.u + 0x7FFF + ((x.u >> 16) & 1);
    return (unsigned short)(r >> 16);
}

typedef __attribute__((address_space(1))) const unsigned char gas_u8;
typedef __attribute__((address_space(3))) unsigned char las_u8;
__device__ __forceinline__ void gload_lds16(const void* g, void* l) {
    __builtin_amdgcn_global_load_lds((gas_u8*)g, (las_u8*)l, 16, 0, 0);
}

// ---------------- weight prep: fp32 src [R][C] -> bf16 dst[c*R + r] = src[r][c] ----------------
__global__ void transpose_k(const float* __restrict__ src, bf16* __restrict__ dst, int R, int C) {
    int idx = blockIdx.x * 256 + threadIdx.x;
    if (idx >= R * C) return;
    int r = idx / C, c = idx % C;
    dst[(size_t)c * R + r] = __float2bfloat16(src[idx]);
}

// ---------------- LayerNorm (wave per token) -> bf16 rows. ----------------
template<bool GATHER>
__global__ __launch_bounds__(256) void ln_k(const float* __restrict__ src,
                                            const float* __restrict__ gamma,
                                            const float* __restrict__ beta,
                                            bf16* __restrict__ dst) {
    int wave = threadIdx.x >> 6, lane = threadIdx.x & 63;
    int t = blockIdx.x * 4 + wave;           // output token index
    size_t srow;
    if (GATHER) {
        int w = t / 49, n = t % 49;
        int b = w >> 6, wl = w & 63, hb = wl >> 3, wb = wl & 7;
        int i = n / 7, j = n % 7;
        int sh = hb * 7 + i + 3; if (sh >= 56) sh -= 56;   // roll(-3): src=(dst+3)%56
        int sw = wb * 7 + j + 3; if (sw >= 56) sw -= 56;
        srow = ((size_t)(b * 56 + sh) * 56 + sw) * CC;
    } else {
        srow = (size_t)t * CC;
    }
    float v[4];
    int c = lane * 4;
    float sum = 0.f, sq = 0.f;
    if (lane < 48) {
        f32x4 d = *(const f32x4*)(src + srow + c);
        #pragma unroll
        for (int q = 0; q < 4; ++q) { v[q] = d[q]; sum += v[q]; sq += v[q] * v[q]; }
    }
    #pragma unroll
    for (int off = 1; off < 64; off <<= 1) { sum += __shfl_xor(sum, off); sq += __shfl_xor(sq, off); }
    float mu = sum * (1.0f / 192.0f);
    float var = sq * (1.0f / 192.0f) - mu * mu;
    float rstd = rsqrtf(var + 1e-5f);
    if (lane < 48) {
        f32x4 gg = *(const f32x4*)(gamma + c);
        f32x4 bb = *(const f32x4*)(beta + c);
        short4v o;
        #pragma unroll
        for (int q = 0; q < 4; ++q) {
            float val = (v[q] - mu) * rstd * gg[q] + bb[q];
            o[q] = (short)f2b(val);
        }
        *(short4v*)(dst + (size_t)t * CC + c) = o;
    }
}

// ---------------- Tiled MFMA GEMM: C[M,N] = X[M,K] @ W[K,N] (+bias, epilogue). WT = W^T [N,K].
// Block: 256 thr (4 waves), tile BM=128 x BN=64, BK=64, double-buffered LDS via global_load_lds
// (linear dest + inverse-swizzled source; reads XOR-swizzled: rule #21 / T2).
// Wave (w1=w>>1, w0=w&1) computes 64x32: 4 m-frags x 2 n-frags of 16x16x32 MFMA.
// D frag: col=lane&15, row=(lane>>4)*4+reg (validated r3/r4).
// grid.x = N/64 (fast axis -> A-tile L2 reuse), grid.y = M/128.
template<int EPI>
__global__ __launch_bounds__(256) void gemm_t(
    const bf16* __restrict__ X, const bf16* __restrict__ WT,
    const float* __restrict__ bias, int K, int N,
    bf16* __restrict__ outb, float* __restrict__ outf,
    const float* __restrict__ xres, const float* __restrict__ yin, int mbase)
{
    __shared__ bf16 As[2][128 * 64];   // 16 KiB each
    __shared__ bf16 Bs[2][64 * 64];    // 8 KiB each
    const int tid = threadIdx.x;
    const int w = tid >> 6, lane = tid & 63;
    const int w0 = w & 1, w1 = w >> 1;
    const int tn0 = blockIdx.x * 64;
    const int tm0 = blockIdx.y * 128;
    const int r16 = lane & 15, g8 = (lane >> 4) * 8;

    auto stage = [&](int buf, int kk) {
        #pragma unroll
        for (int j = 0; j < 4; ++j) {            // A: 1024 chunks of 16B
            int c = (w * 4 + j) * 64 + lane;
            int l = c ^ ((c >> 3) & 7);          // inverse swizzle on source
            const bf16* g = X + (size_t)(tm0 + (c >> 3)) * K + kk + (l & 7) * 8;
            gload_lds16(g, (char*)&As[buf][0] + (size_t)(w * 4 + j) * 1024);
        }
        #pragma unroll
        for (int j = 0; j < 2; ++j) {            // B: 512 chunks
            int c = (w * 2 + j) * 64 + lane;
            int l = c ^ ((c >> 3) & 7);
            const bf16* g = WT + (size_t)(tn0 + (c >> 3)) * K + kk + (l & 7) * 8;
            gload_lds16(g, (char*)&Bs[buf][0] + (size_t)(w * 2 + j) * 1024);
        }
    };

    f32x4 acc[4][2] = {};
    const int nt = K >> 6;
    stage(0, 0);
    __syncthreads();
    for (int t = 0; t < nt; ++t) {
        int buf = t & 1;
        if (t + 1 < nt) stage(buf ^ 1, (t + 1) << 6);
        const char* ab = (const char*)&As[buf][0];
        const char* bb_ = (const char*)&Bs[buf][0];
        #pragma unroll
        for (int k32 = 0; k32 < 2; ++k32) {
            int kcolb = k32 * 64 + g8 * 2;       // byte offset of k-slice
            bf16x8 a[4], b[2];
            #pragma unroll
            for (int m = 0; m < 4; ++m) {
                int row = w1 * 64 + m * 16 + r16;
                int byte = row * 128 + kcolb;
                a[m] = *(const bf16x8*)(ab + (byte ^ ((row & 7) << 4)));
            }
            #pragma unroll
            for (int n = 0; n < 2; ++n) {
                int row = w0 * 32 + n * 16 + r16;
                int byte = row * 128 + kcolb;
                b[n] = *(const bf16x8*)(bb_ + (byte ^ ((row & 7) << 4)));
            }
            #pragma unroll
            for (int m = 0; m < 4; ++m)
                #pragma unroll
                for (int n = 0; n < 2; ++n)
                    acc[m][n] = __builtin_amdgcn_mfma_f32_16x16x32_bf16(a[m], b[n], acc[m][n], 0, 0, 0);
        }
        __syncthreads();
    }

    #pragma unroll
    for (int n = 0; n < 2; ++n) {
        int col = tn0 + w0 * 32 + n * 16 + r16;
        float bv = bias[col];
        #pragma unroll
        for (int m = 0; m < 4; ++m) {
            #pragma unroll
            for (int r = 0; r < 4; ++r) {
                int mm = tm0 + w1 * 64 + m * 16 + (lane >> 4) * 4 + r;
                float val = acc[m][n][r] + bv;
                if (EPI == 0) {
                    outb[(size_t)mm * N + col] = __float2bfloat16(val);
                } else if (EPI == 1) {
                    int gm = mbase + mm;
                    int ww = gm / 49, nn = gm % 49;
                    int b_ = ww >> 6, wl = ww & 63, hb = wl >> 3, wb = wl & 7;
                    int i = nn / 7, j = nn % 7;
                    int oh = hb * 7 + i + 3; if (oh >= 56) oh -= 56;   // roll(+3)
                    int ow = wb * 7 + j + 3; if (ow >= 56) ow -= 56;
                    size_t dst = ((size_t)(b_ * 56 + oh) * 56 + ow) * CC + col;
                    outf[dst] = xres[dst] + val;
                } else if (EPI == 2) {
                    float gv = 0.5f * val * (1.0f + erff(val * 0.70710678118f));
                    outb[(size_t)mm * N + col] = __float2bfloat16(gv);
                } else {
                    outf[(size_t)mm * N + col] = val + yin[(size_t)mm * N + col];
                }
            }
        }
    }
}

// ---------------- Attention: one wave per (window, head). ----------------
__global__ __launch_bounds__(64) void attn_k(const bf16* __restrict__ qkv,
                                             const float* __restrict__ btab,
                                             bf16* __restrict__ out)
{
    int w = blockIdx.x, head = blockIdx.y;
    int tid = threadIdx.x;
    __shared__ float ks[49 * 32];
    __shared__ float vs[49 * 32];
    __shared__ int regid[49];
    for (int idx = tid; idx < 49 * 32; idx += 64) {
        int n = idx >> 5, d = idx & 31;
        size_t base = ((size_t)(w * 49 + n)) * 576 + head * 32 + d;
        ks[idx] = __bfloat162float(qkv[base + 192]);
        vs[idx] = __bfloat162float(qkv[base + 384]);
    }
    if (tid < 49) {
        int wl = w & 63, hb = wl >> 3, wb = wl & 7;
        int i = tid / 7, j = tid % 7;
        int gh = hb * 7 + i, gw = wb * 7 + j;
        int rh = gh < 49 ? 0 : (gh < 53 ? 1 : 2);
        int rw = gw < 49 ? 0 : (gw < 53 ? 1 : 2);
        regid[tid] = rh * 3 + rw;
    }
    __syncthreads();
    if (tid >= 49) return;
    int ln = tid;
    float q[32];
    {
        size_t base = ((size_t)(w * 49 + ln)) * 576 + head * 32;
        const float scale = 0.17677669529663689f;  // 32^-0.5
        #pragma unroll
        for (int d = 0; d < 32; ++d) q[d] = __bfloat162float(qkv[base + d]) * scale;
    }
    int i1 = ln / 7, j1 = ln % 7;
    int myreg = regid[ln];
    float s[49];
    #pragma unroll
    for (int m = 0; m < 49; ++m) {
        float acc = 0.f;
        #pragma unroll
        for (int d = 0; d < 32; ++d) acc += q[d] * ks[m * 32 + d];
        const int i2 = m / 7, j2 = m % 7;
        int bidx = (i1 - i2 + 6) * 13 + (j1 - j2 + 6);
        acc += btab[bidx * 6 + head];
        if (regid[m] != myreg) acc -= 100.0f;
        s[m] = acc;
    }
    float mx = -1e30f;
    #pragma unroll
    for (int m = 0; m < 49; ++m) mx = fmaxf(mx, s[m]);
    float ssum = 0.f;
    #pragma unroll
    for (int m = 0; m < 49; ++m) { s[m] = __expf(s[m] - mx); ssum += s[m]; }
    float inv = 1.0f / ssum;
    float o[32];
    #pragma unroll
    for (int d = 0; d < 32; ++d) o[d] = 0.f;
    #pragma unroll
    for (int m = 0; m < 49; ++m) {
        float p = s[m];
        #pragma unroll
        for (int d = 0; d < 32; ++d) o[d] += p * vs[m * 32 + d];
    }
    size_t ob = ((size_t)(w * 49 + ln)) * CC + head * 32;
    #pragma unroll
    for (int d = 0; d < 32; ++d) out[ob + d] = __float2bfloat16(o[d] * inv);
}

// ---------------- launch ----------------
extern "C" void kernel_launch(void* const* d_in, const int* in_sizes, int n_in,
                              void* d_out, int out_size, void* d_ws, size_t ws_size,
                              hipStream_t stream) {
    const float* x      = (const float*)d_in[0];
    const float* n1g    = (const float*)d_in[1];
    const float* n1b    = (const float*)d_in[2];
    const float* qkv_w  = (const float*)d_in[3];
    const float* qkv_b  = (const float*)d_in[4];
    const float* proj_w = (const float*)d_in[5];
    const float* proj_b = (const float*)d_in[6];
    const float* btab   = (const float*)d_in[7];
    const float* n2g    = (const float*)d_in[8];
    const float* n2b    = (const float*)d_in[9];
    const float* fc1_w  = (const float*)d_in[10];
    const float* fc1_b  = (const float*)d_in[11];
    const float* fc2_w  = (const float*)d_in[12];
    const float* fc2_b  = (const float*)d_in[13];

    char* ws = (char*)d_ws;
    // UNCHUNKED layout (ws_size ~308 MB per round-6 fill evidence; need 193.6 MB):
    //  xw   [0, 38535168)            bf16 [100352][192]  (LN1 out; reused as LN2 out m)
    //  qkv  [38535168, 154140672)    bf16 [100352][576]
    //        (MLP phase: hid bf16 [100352][768] reuses [38535168, 192675840))
    //  att  [154140672, 192675840)   bf16 [100352][192]
    //  wt   [192675840, 193560576)   transposed bf16 weights
    //  y (fp32) lives in d_out: EPI1 writes every element once, EPI3 RMWs once.
    const size_t XW_OFF  = 0;
    const size_t QKV_OFF = 38535168;
    const size_t ATT_OFF = 154140672;
    const size_t WT_OFF  = 192675840;
    if (ws_size < 193560576ull) return;   // diagnostic: zeros signature (absmax ~5.59)

    bf16* xw   = (bf16*)(ws + XW_OFF);
    bf16* mbuf = (bf16*)(ws + XW_OFF);       // reuses xw after attn phase
    bf16* qkvb = (bf16*)(ws + QKV_OFF);
    bf16* attb = (bf16*)(ws + ATT_OFF);
    bf16* hidb = (bf16*)(ws + QKV_OFF);      // MLP phase reuse (152 MB region)
    float* yf  = (float*)d_out;              // fp32 residual accumulator == final output
    bf16* wt   = (bf16*)(ws + WT_OFF);
    bf16* qkv_wT  = wt;                       // [576][192]
    bf16* proj_wT = wt + 110592;              // [192][192]
    bf16* fc1_wT  = wt + 147456;              // [768][192]
    bf16* fc2_wT  = wt + 294912;              // [192][768]

    transpose_k<<<dim3(432), 256, 0, stream>>>(qkv_w, qkv_wT, 192, 576);
    transpose_k<<<dim3(144), 256, 0, stream>>>(proj_w, proj_wT, 192, 192);
    transpose_k<<<dim3(576), 256, 0, stream>>>(fc1_w, fc1_wT, 192, 768);
    transpose_k<<<dim3(576), 256, 0, stream>>>(fc2_w, fc2_wT, 768, 192);

    ln_k<true><<<NTOK / 4, 256, 0, stream>>>(x, n1g, n1b, xw);

    gemm_t<0><<<dim3(9, 784), 256, 0, stream>>>(
        xw, qkv_wT, qkv_b, 192, 576, qkvb, nullptr, nullptr, nullptr, 0);
    attn_k<<<dim3(2048, 6), 64, 0, stream>>>(qkvb, btab, attb);
    gemm_t<1><<<dim3(3, 784), 256, 0, stream>>>(
        attb, proj_wT, proj_b, 192, 192, nullptr, yf, x, nullptr, 0);

    ln_k<false><<<NTOK / 4, 256, 0, stream>>>(yf, n2g, n2b, mbuf);

    gemm_t<2><<<dim3(12, 784), 256, 0, stream>>>(
        mbuf, fc1_wT, fc1_b, 192, 768, hidb, nullptr, nullptr, nullptr, 0);
    gemm_t<3><<<dim3(3, 784), 256, 0, stream>>>(
        hidb, fc2_wT, fc2_b, 768, 192, nullptr, yf, nullptr, yf, 0);
}

// Round 8
// 408.685 us; speedup vs baseline: 3.0606x; 1.1571x over previous
//
#include <hip/hip_runtime.h>
#include <hip/hip_bf16.h>

typedef __hip_bfloat16 bf16;
typedef float f32x4 __attribute__((ext_vector_type(4)));
typedef short bf16x8 __attribute__((ext_vector_type(8)));
typedef short short4v __attribute__((ext_vector_type(4)));
typedef unsigned int u32;

#define NTOK 100352   // 32*56*56 tokens = 2048 windows * 49
#define CC 192
#define HIDN 768

__device__ __forceinline__ float b2f(unsigned short u) {
    union { unsigned int u32v; float f; } x; x.u32v = ((unsigned int)u) << 16; return x.f;
}
__device__ __forceinline__ unsigned short f2b(float f) {
    union { float f; unsigned int u; } x; x.f = f;
    unsigned int r = x.u + 0x7FFF + ((x.u >> 16) & 1);
    return (unsigned short)(r >> 16);
}

typedef __attribute__((address_space(1))) const unsigned char gas_u8;
typedef __attribute__((address_space(3))) unsigned char las_u8;
__device__ __forceinline__ void gload_lds16(const void* g, void* l) {
    __builtin_amdgcn_global_load_lds((gas_u8*)g, (las_u8*)l, 16, 0, 0);
}

// ---------------- weight prep: fp32 src [R][C] -> bf16 dst[c*R + r] = src[r][c] ----------------
__global__ void transpose_k(const float* __restrict__ src, bf16* __restrict__ dst, int R, int C) {
    int idx = blockIdx.x * 256 + threadIdx.x;
    if (idx >= R * C) return;
    int r = idx / C, c = idx % C;
    dst[(size_t)c * R + r] = __float2bfloat16(src[idx]);
}

// ---------------- biasmask table: [cls][head][mt][nt][lane][reg] f32, acc-frag layout.
// kk = key idx (D row), q = query idx (D col). -1e9 outside 49x49. ----------------
__global__ void bm_k(const float* __restrict__ btab, float* __restrict__ bm) {
    int idx = blockIdx.x * 256 + threadIdx.x;           // 4*6*16*256 = 98304
    if (idx >= 98304) return;
    int reg = idx & 3, lane = (idx >> 2) & 63, tile = (idx >> 8) & 15;
    int rest = idx >> 12, h = rest % 6, cls = rest / 6;
    int mt = tile >> 2, nt = tile & 3;
    int kk = mt * 16 + (lane >> 4) * 4 + reg;
    int q  = nt * 16 + (lane & 15);
    float v;
    if (kk >= 49 || q >= 49) v = -1e9f;
    else {
        int i1 = q / 7, j1 = q % 7, i2 = kk / 7, j2 = kk % 7;
        v = btab[((i1 - i2 + 6) * 13 + (j1 - j2 + 6)) * 6 + h];
        int hb7 = cls >> 1, wb7 = cls & 1;
        int r1 = (hb7 ? (i1 < 4 ? 1 : 2) : 0) * 3 + (wb7 ? (j1 < 4 ? 1 : 2) : 0);
        int r2 = (hb7 ? (i2 < 4 ? 1 : 2) : 0) * 3 + (wb7 ? (j2 < 4 ? 1 : 2) : 0);
        if (r1 != r2) v -= 100.0f;
    }
    bm[idx] = v;
}

// ---------------- LayerNorm (wave per token) -> bf16 rows. ----------------
template<bool GATHER>
__global__ __launch_bounds__(256) void ln_k(const float* __restrict__ src,
                                            const float* __restrict__ gamma,
                                            const float* __restrict__ beta,
                                            bf16* __restrict__ dst) {
    int wave = threadIdx.x >> 6, lane = threadIdx.x & 63;
    int t = blockIdx.x * 4 + wave;           // output token index
    size_t srow;
    if (GATHER) {
        int w = t / 49, n = t % 49;
        int b = w >> 6, wl = w & 63, hb = wl >> 3, wb = wl & 7;
        int i = n / 7, j = n % 7;
        int sh = hb * 7 + i + 3; if (sh >= 56) sh -= 56;   // roll(-3): src=(dst+3)%56
        int sw = wb * 7 + j + 3; if (sw >= 56) sw -= 56;
        srow = ((size_t)(b * 56 + sh) * 56 + sw) * CC;
    } else {
        srow = (size_t)t * CC;
    }
    float v[4];
    int c = lane * 4;
    float sum = 0.f, sq = 0.f;
    if (lane < 48) {
        f32x4 d = *(const f32x4*)(src + srow + c);
        #pragma unroll
        for (int q = 0; q < 4; ++q) { v[q] = d[q]; sum += v[q]; sq += v[q] * v[q]; }
    }
    #pragma unroll
    for (int off = 1; off < 64; off <<= 1) { sum += __shfl_xor(sum, off); sq += __shfl_xor(sq, off); }
    float mu = sum * (1.0f / 192.0f);
    float var = sq * (1.0f / 192.0f) - mu * mu;
    float rstd = rsqrtf(var + 1e-5f);
    if (lane < 48) {
        f32x4 gg = *(const f32x4*)(gamma + c);
        f32x4 bb = *(const f32x4*)(beta + c);
        short4v o;
        #pragma unroll
        for (int q = 0; q < 4; ++q) {
            float val = (v[q] - mu) * rstd * gg[q] + bb[q];
            o[q] = (short)f2b(val);
        }
        *(short4v*)(dst + (size_t)t * CC + c) = o;
    }
}

// ---------------- Tiled MFMA GEMM (128x64 tile, BK=64, dbuf LDS, swizzled). ----------------
// EPI 0: +bias -> bf16 outb [M][N]
// EPI 1: +bias, window-reverse+roll(+3,+3) scatter, outf[dst] = xres[dst] + val
// EPI 2: +bias, exact gelu -> bf16 outb
// EPI 3: +bias + yin(fp32) -> fp32 outf
// EPI 4: +bias -> head-planar bf16: outb[((col>>5)*NTOK + m)*32 + (col&31)]
template<int EPI>
__global__ __launch_bounds__(256) void gemm_t(
    const bf16* __restrict__ X, const bf16* __restrict__ WT,
    const float* __restrict__ bias, int K, int N,
    bf16* __restrict__ outb, float* __restrict__ outf,
    const float* __restrict__ xres, const float* __restrict__ yin, int mbase)
{
    __shared__ bf16 As[2][128 * 64];
    __shared__ bf16 Bs[2][64 * 64];
    const int tid = threadIdx.x;
    const int w = tid >> 6, lane = tid & 63;
    const int w0 = w & 1, w1 = w >> 1;
    const int tn0 = blockIdx.x * 64;
    const int tm0 = blockIdx.y * 128;
    const int r16 = lane & 15, g8 = (lane >> 4) * 8;

    auto stage = [&](int buf, int kk) {
        #pragma unroll
        for (int j = 0; j < 4; ++j) {
            int c = (w * 4 + j) * 64 + lane;
            int l = c ^ ((c >> 3) & 7);
            const bf16* g = X + (size_t)(tm0 + (c >> 3)) * K + kk + (l & 7) * 8;
            gload_lds16(g, (char*)&As[buf][0] + (size_t)(w * 4 + j) * 1024);
        }
        #pragma unroll
        for (int j = 0; j < 2; ++j) {
            int c = (w * 2 + j) * 64 + lane;
            int l = c ^ ((c >> 3) & 7);
            const bf16* g = WT + (size_t)(tn0 + (c >> 3)) * K + kk + (l & 7) * 8;
            gload_lds16(g, (char*)&Bs[buf][0] + (size_t)(w * 2 + j) * 1024);
        }
    };

    f32x4 acc[4][2] = {};
    const int nt = K >> 6;
    stage(0, 0);
    __syncthreads();
    for (int t = 0; t < nt; ++t) {
        int buf = t & 1;
        if (t + 1 < nt) stage(buf ^ 1, (t + 1) << 6);
        const char* ab = (const char*)&As[buf][0];
        const char* bb_ = (const char*)&Bs[buf][0];
        #pragma unroll
        for (int k32 = 0; k32 < 2; ++k32) {
            int kcolb = k32 * 64 + g8 * 2;
            bf16x8 a[4], b[2];
            #pragma unroll
            for (int m = 0; m < 4; ++m) {
                int row = w1 * 64 + m * 16 + r16;
                int byte = row * 128 + kcolb;
                a[m] = *(const bf16x8*)(ab + (byte ^ ((row & 7) << 4)));
            }
            #pragma unroll
            for (int n = 0; n < 2; ++n) {
                int row = w0 * 32 + n * 16 + r16;
                int byte = row * 128 + kcolb;
                b[n] = *(const bf16x8*)(bb_ + (byte ^ ((row & 7) << 4)));
            }
            #pragma unroll
            for (int m = 0; m < 4; ++m)
                #pragma unroll
                for (int n = 0; n < 2; ++n)
                    acc[m][n] = __builtin_amdgcn_mfma_f32_16x16x32_bf16(a[m], b[n], acc[m][n], 0, 0, 0);
        }
        __syncthreads();
    }

    #pragma unroll
    for (int n = 0; n < 2; ++n) {
        int col = tn0 + w0 * 32 + n * 16 + r16;
        float bv = bias[col];
        #pragma unroll
        for (int m = 0; m < 4; ++m) {
            #pragma unroll
            for (int r = 0; r < 4; ++r) {
                int mm = tm0 + w1 * 64 + m * 16 + (lane >> 4) * 4 + r;
                float val = acc[m][n][r] + bv;
                if (EPI == 0) {
                    outb[(size_t)mm * N + col] = __float2bfloat16(val);
                } else if (EPI == 1) {
                    int gm = mbase + mm;
                    int ww = gm / 49, nn = gm % 49;
                    int b_ = ww >> 6, wl = ww & 63, hb = wl >> 3, wb = wl & 7;
                    int i = nn / 7, j = nn % 7;
                    int oh = hb * 7 + i + 3; if (oh >= 56) oh -= 56;   // roll(+3)
                    int ow = wb * 7 + j + 3; if (ow >= 56) ow -= 56;
                    size_t dst = ((size_t)(b_ * 56 + oh) * 56 + ow) * CC + col;
                    outf[dst] = xres[dst] + val;
                } else if (EPI == 2) {
                    float gv = 0.5f * val * (1.0f + erff(val * 0.70710678118f));
                    outb[(size_t)mm * N + col] = __float2bfloat16(gv);
                } else if (EPI == 3) {
                    outf[(size_t)mm * N + col] = val + yin[(size_t)mm * N + col];
                } else {
                    outb[((size_t)(col >> 5) * NTOK + mm) * 32 + (col & 31)] = __float2bfloat16(val);
                }
            }
        }
    }
}

// ---------------- MFMA attention: block = 1 window (384 thr = 6 waves, one per head).
// qkv head-planar [3][6][NTOK][32]. Per head: S(64x64 padded) = K-frags x Q-frags MFMA;
// softmax in-reg (D rows = kk); P -> wave-private swizzled LDS; V^T staged swizzled+zero-pad;
// PV MFMA; scale 1/sum via shfl. biasmask table pre-folded per window class. No barriers. ----------------
__global__ __launch_bounds__(384) void attn_m(const bf16* __restrict__ qkv,
                                              const float* __restrict__ bm,
                                              bf16* __restrict__ out)
{
    __shared__ char Pl[6][8192];    // P[q][kk] bf16, byte = q*128+kk*2 ^ ((q&7)<<4)
    __shared__ char Vt[6][4096];    // V^T[d][kk] bf16, byte = d*128+kk*2 ^ ((d&7)<<4)
    const int w = blockIdx.x;
    const int h = threadIdx.x >> 6, l = threadIdx.x & 63;
    const int w49 = w * 49;
    const int wl = w & 63;
    const int cls = (((wl >> 3) == 7) ? 2 : 0) + (((wl & 7) == 7) ? 1 : 0);
    const int hi8 = (l >> 4) * 8, lo = l & 15;

    // ---- stage V^T (zero-pad kk>=49) ----
    {
        const bf16* vbase = qkv + ((size_t)(12 + h) * NTOK + w49) * 32;
        #pragma unroll
        for (int it = 0; it < 4; ++it) {
            int c = it * 64 + l;                 // [0,256): kk=c>>2, 8-elem group c&3
            int kk = c >> 2, off = (c & 3) * 8;
            bf16x8 v = {};
            if (c < 196) v = *(const bf16x8*)(vbase + kk * 32 + off);
            #pragma unroll
            for (int j = 0; j < 8; ++j) {
                int d = off + j;
                int byte = (d * 128 + kk * 2) ^ ((d & 7) << 4);
                *(bf16*)(&Vt[h][0] + byte) = ((const bf16*)&v)[j];
            }
        }
    }

    // ---- QK^T: D[kk][q], 4x4 tiles of 16x16, K=32 ----
    const bf16* qb = qkv + ((size_t)h * NTOK + w49) * 32 + hi8;
    const bf16* kb = qkv + ((size_t)(6 + h) * NTOK + w49) * 32 + hi8;
    bf16x8 af[4], bf_[4];
    #pragma unroll
    for (int mt = 0; mt < 4; ++mt) af[mt] = *(const bf16x8*)(kb + (size_t)(mt * 16 + lo) * 32);
    #pragma unroll
    for (int ntt = 0; ntt < 4; ++ntt) bf_[ntt] = *(const bf16x8*)(qb + (size_t)(ntt * 16 + lo) * 32);
    f32x4 acc[4][4] = {};
    #pragma unroll
    for (int mt = 0; mt < 4; ++mt)
        #pragma unroll
        for (int ntt = 0; ntt < 4; ++ntt)
            acc[mt][ntt] = __builtin_amdgcn_mfma_f32_16x16x32_bf16(af[mt], bf_[ntt], acc[mt][ntt], 0, 0, 0);

    // ---- scale + biasmask ----
    const float scale = 0.17677669529663689f;   // 32^-0.5
    const float* bmb = bm + ((size_t)(cls * 6 + h) << 4) * 256;
    #pragma unroll
    for (int mt = 0; mt < 4; ++mt)
        #pragma unroll
        for (int ntt = 0; ntt < 4; ++ntt) {
            f32x4 bmv = *(const f32x4*)(bmb + (mt * 4 + ntt) * 256 + l * 4);
            #pragma unroll
            for (int r = 0; r < 4; ++r) acc[mt][ntt][r] = acc[mt][ntt][r] * scale + bmv[r];
        }

    // ---- softmax over kk (rows) per q (col): in-reg over mt,r then shfl over l>>4 ----
    float inv[4], mx[4];
    #pragma unroll
    for (int ntt = 0; ntt < 4; ++ntt) {
        float m_ = -1e30f;
        #pragma unroll
        for (int mt = 0; mt < 4; ++mt)
            #pragma unroll
            for (int r = 0; r < 4; ++r) m_ = fmaxf(m_, acc[mt][ntt][r]);
        m_ = fmaxf(m_, __shfl_xor(m_, 16));
        m_ = fmaxf(m_, __shfl_xor(m_, 32));
        mx[ntt] = m_;
    }
    #pragma unroll
    for (int ntt = 0; ntt < 4; ++ntt) {
        float s_ = 0.f;
        #pragma unroll
        for (int mt = 0; mt < 4; ++mt)
            #pragma unroll
            for (int r = 0; r < 4; ++r) {
                float e = __expf(acc[mt][ntt][r] - mx[ntt]);
                acc[mt][ntt][r] = e;
                s_ += e;
            }
        s_ += __shfl_xor(s_, 16);
        s_ += __shfl_xor(s_, 32);
        inv[ntt] = 1.0f / s_;
    }

    // ---- P -> LDS (packed b32 writes; kk pairs adjacent) ----
    #pragma unroll
    for (int mt = 0; mt < 4; ++mt)
        #pragma unroll
        for (int ntt = 0; ntt < 4; ++ntt)
            #pragma unroll
            for (int rp = 0; rp < 4; rp += 2) {
                u32 pk = (u32)f2b(acc[mt][ntt][rp]) | ((u32)f2b(acc[mt][ntt][rp + 1]) << 16);
                int kk = mt * 16 + (l >> 4) * 4 + rp;
                int q  = ntt * 16 + lo;
                int byte = (q * 128 + kk * 2) ^ ((q & 7) << 4);
                *(u32*)(&Pl[h][0] + byte) = pk;
            }

    // ---- PV: O[q][d] = P[q][kk] @ V^T rows, K=64 (2 steps) ----
    f32x4 o[4][2] = {};
    #pragma unroll
    for (int ks = 0; ks < 2; ++ks) {
        int kb_ = (ks * 32 + hi8) * 2;
        bf16x8 pa[4], vb[2];
        #pragma unroll
        for (int qt = 0; qt < 4; ++qt) {
            int row = qt * 16 + lo;
            pa[qt] = *(const bf16x8*)(&Pl[h][0] + ((row * 128 + kb_) ^ ((row & 7) << 4)));
        }
        #pragma unroll
        for (int dt = 0; dt < 2; ++dt) {
            int row = dt * 16 + lo;
            vb[dt] = *(const bf16x8*)(&Vt[h][0] + ((row * 128 + kb_) ^ ((row & 7) << 4)));
        }
        #pragma unroll
        for (int qt = 0; qt < 4; ++qt)
            #pragma unroll
            for (int dt = 0; dt < 2; ++dt)
                o[qt][dt] = __builtin_amdgcn_mfma_f32_16x16x32_bf16(pa[qt], vb[dt], o[qt][dt], 0, 0, 0);
    }

    // ---- scale by 1/sum (shfl broadcast) and store ----
    #pragma unroll
    for (int qt = 0; qt < 4; ++qt)
        #pragma unroll
        for (int r = 0; r < 4; ++r) {
            int qrow = (l >> 4) * 4 + r;
            float iv = __shfl(inv[qt], qrow);
            int q = qt * 16 + qrow;
            if (q < 49) {
                size_t ob = (size_t)(w49 + q) * CC + h * 32 + lo;
                out[ob]      = __float2bfloat16(o[qt][0][r] * iv);
                out[ob + 16] = __float2bfloat16(o[qt][1][r] * iv);
            }
        }
}

// ---------------- launch ----------------
extern "C" void kernel_launch(void* const* d_in, const int* in_sizes, int n_in,
                              void* d_out, int out_size, void* d_ws, size_t ws_size,
                              hipStream_t stream) {
    const float* x      = (const float*)d_in[0];
    const float* n1g    = (const float*)d_in[1];
    const float* n1b    = (const float*)d_in[2];
    const float* qkv_w  = (const float*)d_in[3];
    const float* qkv_b  = (const float*)d_in[4];
    const float* proj_w = (const float*)d_in[5];
    const float* proj_b = (const float*)d_in[6];
    const float* btab   = (const float*)d_in[7];
    const float* n2g    = (const float*)d_in[8];
    const float* n2b    = (const float*)d_in[9];
    const float* fc1_w  = (const float*)d_in[10];
    const float* fc1_b  = (const float*)d_in[11];
    const float* fc2_w  = (const float*)d_in[12];
    const float* fc2_b  = (const float*)d_in[13];

    char* ws = (char*)d_ws;
    //  xw   [0, 38535168)            bf16 [100352][192]  (LN1 out; reused as LN2 out m)
    //  qkv  [38535168, 154140672)    bf16 head-planar [3][6][NTOK][32]
    //        (MLP phase: hid bf16 [100352][768] reuses [38535168, 192675840))
    //  att  [154140672, 192675840)   bf16 [100352][192]
    //  wt   [192675840, 193560576)   transposed bf16 weights
    //  bm   [193560576, 193953792)   biasmask f32 [4][6][16][256]
    //  y (fp32) lives in d_out.
    const size_t XW_OFF  = 0;
    const size_t QKV_OFF = 38535168;
    const size_t ATT_OFF = 154140672;
    const size_t WT_OFF  = 192675840;
    const size_t BM_OFF  = 193560576;
    if (ws_size < 193953792ull) return;   // diagnostic: zeros signature (absmax ~5.59)

    bf16* xw   = (bf16*)(ws + XW_OFF);
    bf16* mbuf = (bf16*)(ws + XW_OFF);
    bf16* qkvb = (bf16*)(ws + QKV_OFF);
    bf16* attb = (bf16*)(ws + ATT_OFF);
    bf16* hidb = (bf16*)(ws + QKV_OFF);
    float* yf  = (float*)d_out;
    bf16* wt   = (bf16*)(ws + WT_OFF);
    float* bmt = (float*)(ws + BM_OFF);
    bf16* qkv_wT  = wt;
    bf16* proj_wT = wt + 110592;
    bf16* fc1_wT  = wt + 147456;
    bf16* fc2_wT  = wt + 294912;

    transpose_k<<<dim3(432), 256, 0, stream>>>(qkv_w, qkv_wT, 192, 576);
    transpose_k<<<dim3(144), 256, 0, stream>>>(proj_w, proj_wT, 192, 192);
    transpose_k<<<dim3(576), 256, 0, stream>>>(fc1_w, fc1_wT, 192, 768);
    transpose_k<<<dim3(576), 256, 0, stream>>>(fc2_w, fc2_wT, 768, 192);
    bm_k<<<dim3(384), 256, 0, stream>>>(btab, bmt);

    ln_k<true><<<NTOK / 4, 256, 0, stream>>>(x, n1g, n1b, xw);

    gemm_t<4><<<dim3(9, 784), 256, 0, stream>>>(
        xw, qkv_wT, qkv_b, 192, 576, qkvb, nullptr, nullptr, nullptr, 0);
    attn_m<<<dim3(2048), 384, 0, stream>>>(qkvb, bmt, attb);
    gemm_t<1><<<dim3(3, 784), 256, 0, stream>>>(
        attb, proj_wT, proj_b, 192, 192, nullptr, yf, x, nullptr, 0);

    ln_k<false><<<NTOK / 4, 256, 0, stream>>>(yf, n2g, n2b, mbuf);

    gemm_t<2><<<dim3(12, 784), 256, 0, stream>>>(
        mbuf, fc1_wT, fc1_b, 192, 768, hidb, nullptr, nullptr, nullptr, 0);
    gemm_t<3><<<dim3(3, 784), 256, 0, stream>>>(
        hidb, fc2_wT, fc2_b, 768, 192, nullptr, yf, nullptr, yf, 0);
}

// Round 9
// 368.706 us; speedup vs baseline: 3.3925x; 1.1084x over previous
//
#include <hip/hip_runtime.h>
#include <hip/hip_bf16.h>

typedef __hip_bfloat16 bf16;
typedef float f32x4 __attribute__((ext_vector_type(4)));
typedef short bf16x8 __attribute__((ext_vector_type(8)));
typedef short short4v __attribute__((ext_vector_type(4)));
typedef unsigned int u32;

#define NTOK 100352   // 32*56*56 tokens = 2048 windows * 49
#define CC 192
#define HIDN 768

__device__ __forceinline__ float b2f(unsigned short u) {
    union { unsigned int u32v; float f; } x; x.u32v = ((unsigned int)u) << 16; return x.f;
}
__device__ __forceinline__ unsigned short f2b(float f) {
    union { float f; unsigned int u; } x; x.f = f;
    unsigned int r = x.u + 0x7FFF + ((x.u >> 16) & 1);
    return (unsigned short)(r >> 16);
}

typedef __attribute__((address_space(1))) const unsigned char gas_u8;
typedef __attribute__((address_space(3))) unsigned char las_u8;
__device__ __forceinline__ void gload_lds16(const void* g, void* l) {
    __builtin_amdgcn_global_load_lds((gas_u8*)g, (las_u8*)l, 16, 0, 0);
}

// ---------------- weight prep: fp32 src [R][C] -> bf16 dst[c*R + r] = src[r][c] ----------------
__global__ void transpose_k(const float* __restrict__ src, bf16* __restrict__ dst, int R, int C) {
    int idx = blockIdx.x * 256 + threadIdx.x;
    if (idx >= R * C) return;
    int r = idx / C, c = idx % C;
    dst[(size_t)c * R + r] = __float2bfloat16(src[idx]);
}

// ---------------- biasmask table: [cls][head][mt][nt][lane][reg] f32, acc-frag layout. ----------------
__global__ void bm_k(const float* __restrict__ btab, float* __restrict__ bm) {
    int idx = blockIdx.x * 256 + threadIdx.x;           // 4*6*16*256 = 98304
    if (idx >= 98304) return;
    int reg = idx & 3, lane = (idx >> 2) & 63, tile = (idx >> 8) & 15;
    int rest = idx >> 12, h = rest % 6, cls = rest / 6;
    int mt = tile >> 2, nt = tile & 3;
    int kk = mt * 16 + (lane >> 4) * 4 + reg;
    int q  = nt * 16 + (lane & 15);
    float v;
    if (kk >= 49 || q >= 49) v = -1e9f;
    else {
        int i1 = q / 7, j1 = q % 7, i2 = kk / 7, j2 = kk % 7;
        v = btab[((i1 - i2 + 6) * 13 + (j1 - j2 + 6)) * 6 + h];
        int hb7 = cls >> 1, wb7 = cls & 1;
        int r1 = (hb7 ? (i1 < 4 ? 1 : 2) : 0) * 3 + (wb7 ? (j1 < 4 ? 1 : 2) : 0);
        int r2 = (hb7 ? (i2 < 4 ? 1 : 2) : 0) * 3 + (wb7 ? (j2 < 4 ? 1 : 2) : 0);
        if (r1 != r2) v -= 100.0f;
    }
    bm[idx] = v;
}

// ---------------- LayerNorm (wave per token) -> bf16 rows. ----------------
template<bool GATHER>
__global__ __launch_bounds__(256) void ln_k(const float* __restrict__ src,
                                            const float* __restrict__ gamma,
                                            const float* __restrict__ beta,
                                            bf16* __restrict__ dst) {
    int wave = threadIdx.x >> 6, lane = threadIdx.x & 63;
    int t = blockIdx.x * 4 + wave;           // output token index
    size_t srow;
    if (GATHER) {
        int w = t / 49, n = t % 49;
        int b = w >> 6, wl = w & 63, hb = wl >> 3, wb = wl & 7;
        int i = n / 7, j = n % 7;
        int sh = hb * 7 + i + 3; if (sh >= 56) sh -= 56;   // roll(-3): src=(dst+3)%56
        int sw = wb * 7 + j + 3; if (sw >= 56) sw -= 56;
        srow = ((size_t)(b * 56 + sh) * 56 + sw) * CC;
    } else {
        srow = (size_t)t * CC;
    }
    float v[4];
    int c = lane * 4;
    float sum = 0.f, sq = 0.f;
    if (lane < 48) {
        f32x4 d = *(const f32x4*)(src + srow + c);
        #pragma unroll
        for (int q = 0; q < 4; ++q) { v[q] = d[q]; sum += v[q]; sq += v[q] * v[q]; }
    }
    #pragma unroll
    for (int off = 1; off < 64; off <<= 1) { sum += __shfl_xor(sum, off); sq += __shfl_xor(sq, off); }
    float mu = sum * (1.0f / 192.0f);
    float var = sq * (1.0f / 192.0f) - mu * mu;
    float rstd = rsqrtf(var + 1e-5f);
    if (lane < 48) {
        f32x4 gg = *(const f32x4*)(gamma + c);
        f32x4 bb = *(const f32x4*)(beta + c);
        short4v o;
        #pragma unroll
        for (int q = 0; q < 4; ++q) {
            float val = (v[q] - mu) * rstd * gg[q] + bb[q];
            o[q] = (short)f2b(val);
        }
        *(short4v*)(dst + (size_t)t * CC + c) = o;
    }
}

// ---------------- Tiled MFMA GEMM (128x64 tile, BK=64, dbuf LDS, swizzled reads,
// XCD-chunked block swizzle: blocks sharing an A-panel land on one XCD's L2). ----------------
// EPI 0: +bias -> bf16 outb [M][N]
// EPI 1: +bias, window-reverse+roll(+3,+3) scatter, outf[dst] = xres[dst] + val
// EPI 2: +bias, exact gelu -> bf16 outb
// EPI 3: +bias + yin(fp32) -> fp32 outf
// EPI 4: +bias -> head-planar bf16: outb[((col>>5)*NTOK + m)*32 + (col&31)]
template<int EPI>
__global__ __launch_bounds__(256) void gemm_t(
    const bf16* __restrict__ X, const bf16* __restrict__ WT,
    const float* __restrict__ bias, int K, int N,
    bf16* __restrict__ outb, float* __restrict__ outf,
    const float* __restrict__ xres, const float* __restrict__ yin, int mbase)
{
    __shared__ bf16 As[2][128 * 64];
    __shared__ bf16 Bs[2][64 * 64];
    const int tid = threadIdx.x;
    const int w = tid >> 6, lane = tid & 63;
    const int w0 = w & 1, w1 = w >> 1;

    // bijective XCD-chunked swizzle (all grids here have nwg % 8 == 0)
    const u32 nwg = gridDim.x * gridDim.y;
    u32 bid = blockIdx.y * gridDim.x + blockIdx.x;
    if ((nwg & 7) == 0) bid = (bid & 7) * (nwg >> 3) + (bid >> 3);
    const int tn0 = (bid % gridDim.x) * 64;
    const int tm0 = (bid / gridDim.x) * 128;

    const int r16 = lane & 15, g8 = (lane >> 4) * 8;

    // staging addresses hoisted out of the K-loop
    const bf16* gA[4];
    const bf16* gB[2];
    #pragma unroll
    for (int j = 0; j < 4; ++j) {
        int c = (w * 4 + j) * 64 + lane;
        int l = c ^ ((c >> 3) & 7);          // inverse swizzle on source
        gA[j] = X + (size_t)(tm0 + (c >> 3)) * K + (l & 7) * 8;
    }
    #pragma unroll
    for (int j = 0; j < 2; ++j) {
        int c = (w * 2 + j) * 64 + lane;
        int l = c ^ ((c >> 3) & 7);
        gB[j] = WT + (size_t)(tn0 + (c >> 3)) * K + (l & 7) * 8;
    }

    auto stage = [&](int buf, int kk) {
        #pragma unroll
        for (int j = 0; j < 4; ++j)
            gload_lds16(gA[j] + kk, (char*)&As[buf][0] + (size_t)(w * 4 + j) * 1024);
        #pragma unroll
        for (int j = 0; j < 2; ++j)
            gload_lds16(gB[j] + kk, (char*)&Bs[buf][0] + (size_t)(w * 2 + j) * 1024);
    };

    f32x4 acc[4][2] = {};
    const int nt = K >> 6;
    stage(0, 0);
    __syncthreads();
    for (int t = 0; t < nt; ++t) {
        int buf = t & 1;
        if (t + 1 < nt) stage(buf ^ 1, (t + 1) << 6);
        const char* ab = (const char*)&As[buf][0];
        const char* bb_ = (const char*)&Bs[buf][0];
        #pragma unroll
        for (int k32 = 0; k32 < 2; ++k32) {
            int kcolb = k32 * 64 + g8 * 2;
            bf16x8 a[4], b[2];
            #pragma unroll
            for (int m = 0; m < 4; ++m) {
                int row = w1 * 64 + m * 16 + r16;
                int byte = row * 128 + kcolb;
                a[m] = *(const bf16x8*)(ab + (byte ^ ((row & 7) << 4)));
            }
            #pragma unroll
            for (int n = 0; n < 2; ++n) {
                int row = w0 * 32 + n * 16 + r16;
                int byte = row * 128 + kcolb;
                b[n] = *(const bf16x8*)(bb_ + (byte ^ ((row & 7) << 4)));
            }
            #pragma unroll
            for (int m = 0; m < 4; ++m)
                #pragma unroll
                for (int n = 0; n < 2; ++n)
                    acc[m][n] = __builtin_amdgcn_mfma_f32_16x16x32_bf16(a[m], b[n], acc[m][n], 0, 0, 0);
        }
        __syncthreads();
    }

    #pragma unroll
    for (int n = 0; n < 2; ++n) {
        int col = tn0 + w0 * 32 + n * 16 + r16;
        float bv = bias[col];
        #pragma unroll
        for (int m = 0; m < 4; ++m) {
            #pragma unroll
            for (int r = 0; r < 4; ++r) {
                int mm = tm0 + w1 * 64 + m * 16 + (lane >> 4) * 4 + r;
                float val = acc[m][n][r] + bv;
                if (EPI == 0) {
                    outb[(size_t)mm * N + col] = __float2bfloat16(val);
                } else if (EPI == 1) {
                    int gm = mbase + mm;
                    int ww = gm / 49, nn = gm % 49;
                    int b_ = ww >> 6, wl = ww & 63, hb = wl >> 3, wb = wl & 7;
                    int i = nn / 7, j = nn % 7;
                    int oh = hb * 7 + i + 3; if (oh >= 56) oh -= 56;   // roll(+3)
                    int ow = wb * 7 + j + 3; if (ow >= 56) ow -= 56;
                    size_t dst = ((size_t)(b_ * 56 + oh) * 56 + ow) * CC + col;
                    outf[dst] = xres[dst] + val;
                } else if (EPI == 2) {
                    float gv = 0.5f * val * (1.0f + erff(val * 0.70710678118f));
                    outb[(size_t)mm * N + col] = __float2bfloat16(gv);
                } else if (EPI == 3) {
                    outf[(size_t)mm * N + col] = val + yin[(size_t)mm * N + col];
                } else {
                    outb[((size_t)(col >> 5) * NTOK + mm) * 32 + (col & 31)] = __float2bfloat16(val);
                }
            }
        }
    }
}

// ---------------- MFMA attention: block = 1 window (384 thr = 6 waves, one per head). ----------------
__global__ __launch_bounds__(384) void attn_m(const bf16* __restrict__ qkv,
                                              const float* __restrict__ bm,
                                              bf16* __restrict__ out)
{
    __shared__ char Pl[6][8192];    // P[q][kk] bf16, byte = q*128+kk*2 ^ ((q&7)<<4)
    __shared__ char Vt[6][4096];    // V^T[d][kk] bf16, byte = d*128+kk*2 ^ ((d&7)<<4)
    const int w = blockIdx.x;
    const int h = threadIdx.x >> 6, l = threadIdx.x & 63;
    const int w49 = w * 49;
    const int wl = w & 63;
    const int cls = (((wl >> 3) == 7) ? 2 : 0) + (((wl & 7) == 7) ? 1 : 0);
    const int hi8 = (l >> 4) * 8, lo = l & 15;

    // ---- stage V^T (zero-pad kk>=49) ----
    {
        const bf16* vbase = qkv + ((size_t)(12 + h) * NTOK + w49) * 32;
        #pragma unroll
        for (int it = 0; it < 4; ++it) {
            int c = it * 64 + l;                 // [0,256): kk=c>>2, 8-elem group c&3
            int kk = c >> 2, off = (c & 3) * 8;
            bf16x8 v = {};
            if (c < 196) v = *(const bf16x8*)(vbase + kk * 32 + off);
            #pragma unroll
            for (int j = 0; j < 8; ++j) {
                int d = off + j;
                int byte = (d * 128 + kk * 2) ^ ((d & 7) << 4);
                *(bf16*)(&Vt[h][0] + byte) = ((const bf16*)&v)[j];
            }
        }
    }

    // ---- QK^T: D[kk][q], 4x4 tiles of 16x16, K=32 ----
    const bf16* qb = qkv + ((size_t)h * NTOK + w49) * 32 + hi8;
    const bf16* kb = qkv + ((size_t)(6 + h) * NTOK + w49) * 32 + hi8;
    bf16x8 af[4], bf_[4];
    #pragma unroll
    for (int mt = 0; mt < 4; ++mt) af[mt] = *(const bf16x8*)(kb + (size_t)(mt * 16 + lo) * 32);
    #pragma unroll
    for (int ntt = 0; ntt < 4; ++ntt) bf_[ntt] = *(const bf16x8*)(qb + (size_t)(ntt * 16 + lo) * 32);
    f32x4 acc[4][4] = {};
    #pragma unroll
    for (int mt = 0; mt < 4; ++mt)
        #pragma unroll
        for (int ntt = 0; ntt < 4; ++ntt)
            acc[mt][ntt] = __builtin_amdgcn_mfma_f32_16x16x32_bf16(af[mt], bf_[ntt], acc[mt][ntt], 0, 0, 0);

    // ---- scale + biasmask ----
    const float scale = 0.17677669529663689f;   // 32^-0.5
    const float* bmb = bm + ((size_t)(cls * 6 + h) << 4) * 256;
    #pragma unroll
    for (int mt = 0; mt < 4; ++mt)
        #pragma unroll
        for (int ntt = 0; ntt < 4; ++ntt) {
            f32x4 bmv = *(const f32x4*)(bmb + (mt * 4 + ntt) * 256 + l * 4);
            #pragma unroll
            for (int r = 0; r < 4; ++r) acc[mt][ntt][r] = acc[mt][ntt][r] * scale + bmv[r];
        }

    // ---- softmax over kk (rows) per q (col): in-reg over mt,r then shfl over l>>4 ----
    float inv[4], mx[4];
    #pragma unroll
    for (int ntt = 0; ntt < 4; ++ntt) {
        float m_ = -1e30f;
        #pragma unroll
        for (int mt = 0; mt < 4; ++mt)
            #pragma unroll
            for (int r = 0; r < 4; ++r) m_ = fmaxf(m_, acc[mt][ntt][r]);
        m_ = fmaxf(m_, __shfl_xor(m_, 16));
        m_ = fmaxf(m_, __shfl_xor(m_, 32));
        mx[ntt] = m_;
    }
    #pragma unroll
    for (int ntt = 0; ntt < 4; ++ntt) {
        float s_ = 0.f;
        #pragma unroll
        for (int mt = 0; mt < 4; ++mt)
            #pragma unroll
            for (int r = 0; r < 4; ++r) {
                float e = __expf(acc[mt][ntt][r] - mx[ntt]);
                acc[mt][ntt][r] = e;
                s_ += e;
            }
        s_ += __shfl_xor(s_, 16);
        s_ += __shfl_xor(s_, 32);
        inv[ntt] = 1.0f / s_;
    }

    // ---- P -> LDS (packed b32 writes; kk pairs adjacent) ----
    #pragma unroll
    for (int mt = 0; mt < 4; ++mt)
        #pragma unroll
        for (int ntt = 0; ntt < 4; ++ntt)
            #pragma unroll
            for (int rp = 0; rp < 4; rp += 2) {
                u32 pk = (u32)f2b(acc[mt][ntt][rp]) | ((u32)f2b(acc[mt][ntt][rp + 1]) << 16);
                int kk = mt * 16 + (l >> 4) * 4 + rp;
                int q  = ntt * 16 + lo;
                int byte = (q * 128 + kk * 2) ^ ((q & 7) << 4);
                *(u32*)(&Pl[h][0] + byte) = pk;
            }

    // ---- PV: O[q][d] = P[q][kk] @ V^T rows, K=64 (2 steps) ----
    f32x4 o[4][2] = {};
    #pragma unroll
    for (int ks = 0; ks < 2; ++ks) {
        int kb_ = (ks * 32 + hi8) * 2;
        bf16x8 pa[4], vb[2];
        #pragma unroll
        for (int qt = 0; qt < 4; ++qt) {
            int row = qt * 16 + lo;
            pa[qt] = *(const bf16x8*)(&Pl[h][0] + ((row * 128 + kb_) ^ ((row & 7) << 4)));
        }
        #pragma unroll
        for (int dt = 0; dt < 2; ++dt) {
            int row = dt * 16 + lo;
            vb[dt] = *(const bf16x8*)(&Vt[h][0] + ((row * 128 + kb_) ^ ((row & 7) << 4)));
        }
        #pragma unroll
        for (int qt = 0; qt < 4; ++qt)
            #pragma unroll
            for (int dt = 0; dt < 2; ++dt)
                o[qt][dt] = __builtin_amdgcn_mfma_f32_16x16x32_bf16(pa[qt], vb[dt], o[qt][dt], 0, 0, 0);
    }

    // ---- scale by 1/sum (shfl broadcast) and store ----
    #pragma unroll
    for (int qt = 0; qt < 4; ++qt)
        #pragma unroll
        for (int r = 0; r < 4; ++r) {
            int qrow = (l >> 4) * 4 + r;
            float iv = __shfl(inv[qt], qrow);
            int q = qt * 16 + qrow;
            if (q < 49) {
                size_t ob = (size_t)(w49 + q) * CC + h * 32 + lo;
                out[ob]      = __float2bfloat16(o[qt][0][r] * iv);
                out[ob + 16] = __float2bfloat16(o[qt][1][r] * iv);
            }
        }
}

// ---------------- launch ----------------
extern "C" void kernel_launch(void* const* d_in, const int* in_sizes, int n_in,
                              void* d_out, int out_size, void* d_ws, size_t ws_size,
                              hipStream_t stream) {
    const float* x      = (const float*)d_in[0];
    const float* n1g    = (const float*)d_in[1];
    const float* n1b    = (const float*)d_in[2];
    const float* qkv_w  = (const float*)d_in[3];
    const float* qkv_b  = (const float*)d_in[4];
    const float* proj_w = (const float*)d_in[5];
    const float* proj_b = (const float*)d_in[6];
    const float* btab   = (const float*)d_in[7];
    const float* n2g    = (const float*)d_in[8];
    const float* n2b    = (const float*)d_in[9];
    const float* fc1_w  = (const float*)d_in[10];
    const float* fc1_b  = (const float*)d_in[11];
    const float* fc2_w  = (const float*)d_in[12];
    const float* fc2_b  = (const float*)d_in[13];

    char* ws = (char*)d_ws;
    //  xw   [0, 38535168)            bf16 [100352][192]  (LN1 out; reused as LN2 out m)
    //  qkv  [38535168, 154140672)    bf16 head-planar [3][6][NTOK][32]
    //        (MLP phase: hid bf16 [100352][768] reuses [38535168, 192675840))
    //  att  [154140672, 192675840)   bf16 [100352][192]
    //  wt   [192675840, 193560576)   transposed bf16 weights
    //  bm   [193560576, 193953792)   biasmask f32 [4][6][16][256]
    //  y (fp32) lives in d_out.
    const size_t XW_OFF  = 0;
    const size_t QKV_OFF = 38535168;
    const size_t ATT_OFF = 154140672;
    const size_t WT_OFF  = 192675840;
    const size_t BM_OFF  = 193560576;
    if (ws_size < 193953792ull) return;   // diagnostic: zeros signature (absmax ~5.59)

    bf16* xw   = (bf16*)(ws + XW_OFF);
    bf16* mbuf = (bf16*)(ws + XW_OFF);
    bf16* qkvb = (bf16*)(ws + QKV_OFF);
    bf16* attb = (bf16*)(ws + ATT_OFF);
    bf16* hidb = (bf16*)(ws + QKV_OFF);
    float* yf  = (float*)d_out;
    bf16* wt   = (bf16*)(ws + WT_OFF);
    float* bmt = (float*)(ws + BM_OFF);
    bf16* qkv_wT  = wt;
    bf16* proj_wT = wt + 110592;
    bf16* fc1_wT  = wt + 147456;
    bf16* fc2_wT  = wt + 294912;

    transpose_k<<<dim3(432), 256, 0, stream>>>(qkv_w, qkv_wT, 192, 576);
    transpose_k<<<dim3(144), 256, 0, stream>>>(proj_w, proj_wT, 192, 192);
    transpose_k<<<dim3(576), 256, 0, stream>>>(fc1_w, fc1_wT, 192, 768);
    transpose_k<<<dim3(576), 256, 0, stream>>>(fc2_w, fc2_wT, 768, 192);
    bm_k<<<dim3(384), 256, 0, stream>>>(btab, bmt);

    ln_k<true><<<NTOK / 4, 256, 0, stream>>>(x, n1g, n1b, xw);

    gemm_t<4><<<dim3(9, 784), 256, 0, stream>>>(
        xw, qkv_wT, qkv_b, 192, 576, qkvb, nullptr, nullptr, nullptr, 0);
    attn_m<<<dim3(2048), 384, 0, stream>>>(qkvb, bmt, attb);
    gemm_t<1><<<dim3(3, 784), 256, 0, stream>>>(
        attb, proj_wT, proj_b, 192, 192, nullptr, yf, x, nullptr, 0);

    ln_k<false><<<NTOK / 4, 256, 0, stream>>>(yf, n2g, n2b, mbuf);

    gemm_t<2><<<dim3(12, 784), 256, 0, stream>>>(
        mbuf, fc1_wT, fc1_b, 192, 768, hidb, nullptr, nullptr, nullptr, 0);
    gemm_t<3><<<dim3(3, 784), 256, 0, stream>>>(
        hidb, fc2_wT, fc2_b, 768, 192, nullptr, yf, nullptr, yf, 0);
}